// Round 4
// baseline (1316.580 us; speedup 1.0000x reference)
//
#include <hip/hip_runtime.h>

typedef _Float16 f16x8 __attribute__((ext_vector_type(8)));
typedef float f32x4 __attribute__((ext_vector_type(4)));
typedef unsigned int u32;

#define EPS 1e-5f

__device__ __forceinline__ short f2h(float x) {
    _Float16 h = (_Float16)x;   // RNE v_cvt_f16_f32
    union { _Float16 h; short s; } u;
    u.h = h;
    return u.s;
}

// async global->LDS DMA, 16 B per lane. LDS dest = wave-uniform base + lane*16.
__device__ __forceinline__ void gl_lds16(const void* g, void* l) {
    __builtin_amdgcn_global_load_lds(
        (const __attribute__((address_space(1))) u32*)g,
        (__attribute__((address_space(3))) u32*)l, 16, 0, 0);
}

// ---------------------------------------------------------------------------
// prep: output-linear transpose+convert. WtM[l][f][k] fp16 <- Wm[l][k][f],
// WtF[f][k] fp16 (f padded to 48), stats zeroed.
// ---------------------------------------------------------------------------
__global__ __launch_bounds__(256) void prep_kernel(
        const float* __restrict__ Wm, const float* __restrict__ Wl,
        short* __restrict__ WtM, short* __restrict__ WtF,
        float* __restrict__ stats) {
    const long T1 = 14L * 896 * 128;
    const long T2 = 48L * 896;
    const long T3 = 15L * 256;
    long i = (long)blockIdx.x * blockDim.x + threadIdx.x;
    if (i < T1) {
        long l = i / 114688;
        long r = i % 114688;
        long f = r / 896;
        long k = r % 896;
        WtM[i] = f2h(Wm[l * 114688 + k * 128 + f]);
    } else if (i < T1 + T2) {
        long j = i - T1;
        long f = j / 896;
        long k = j % 896;
        WtF[j] = (f < 36) ? f2h(Wl[k * 36 + f]) : (short)0;
    } else if (i < T1 + T2 + T3) {
        stats[i - T1 - T2] = 0.0f;
    }
}

// ---------------------------------------------------------------------------
// layer0: wave-per-node, barrier-free after W0 staging. lane covers feats
// (lane, lane+64). Writes fp16 pre-BN h_lin + fp32 stats.
// ---------------------------------------------------------------------------
__global__ __launch_bounds__(256) void layer0_kernel(
        const float* __restrict__ x, const int* __restrict__ idx,
        const float* __restrict__ W0, const float* __restrict__ b0,
        unsigned short* __restrict__ h16, float* __restrict__ stats, int N) {
    __shared__ float sW[21 * 128];
    __shared__ float sstat[256];
    const int tid = threadIdx.x;
    const int lane = tid & 63;
    const int wave = tid >> 6;
    for (int i = tid; i < 21 * 128; i += 256) sW[i] = W0[i];
    sstat[tid] = 0.f;
    __syncthreads();

    const int f0 = lane, f1 = lane + 64;
    const float bb0 = b0[f0], bb1 = b0[f1];
    float s0 = 0.f, ss0 = 0.f, s1 = 0.f, ss1 = 0.f;

    const int gw = blockIdx.x * 4 + wave;
    const int nw = gridDim.x * 4;
    for (int n = gw; n < N; n += nw) {
        float a0 = bb0, a1 = bb1;
#pragma unroll
        for (int j = 0; j < 7; ++j) {
            int r = idx[n * 7 + j];
            float x0 = x[(long)r * 3 + 0];
            float x1 = x[(long)r * 3 + 1];
            float x2 = x[(long)r * 3 + 2];
            int k = j * 3;
            a0 = fmaf(x0, sW[(k + 0) * 128 + f0], a0);
            a0 = fmaf(x1, sW[(k + 1) * 128 + f0], a0);
            a0 = fmaf(x2, sW[(k + 2) * 128 + f0], a0);
            a1 = fmaf(x0, sW[(k + 0) * 128 + f1], a1);
            a1 = fmaf(x1, sW[(k + 1) * 128 + f1], a1);
            a1 = fmaf(x2, sW[(k + 2) * 128 + f1], a1);
        }
        h16[(long)n * 128 + f0] = (unsigned short)f2h(a0);
        h16[(long)n * 128 + f1] = (unsigned short)f2h(a1);
        s0 += a0; ss0 += a0 * a0;
        s1 += a1; ss1 += a1 * a1;
    }
    atomicAdd(&sstat[f0], s0);
    atomicAdd(&sstat[128 + f0], ss0);
    atomicAdd(&sstat[f1], s1);
    atomicAdd(&sstat[128 + f1], ss1);
    __syncthreads();
    if (tid < 256) atomicAdd(&stats[tid], sstat[tid]);
}

// ---------------------------------------------------------------------------
// bn_relu: fp16 in (pre-BN), fp16 out = relu(sc*h + sh). 8 B/thread/iter.
// ---------------------------------------------------------------------------
__global__ __launch_bounds__(256) void bn_relu_kernel(
        const unsigned short* __restrict__ h16, const float* __restrict__ stats,
        const float* __restrict__ g, const float* __restrict__ be,
        unsigned short* __restrict__ hout, int total4, float invN) {
    __shared__ float sSc[128], sSh[128];
    const int tid = threadIdx.x;
    if (tid < 128) {
        float mu = stats[tid] * invN;
        float var = stats[128 + tid] * invN - mu * mu;
        float rs = rsqrtf(var + EPS);
        float sc = g[tid] * rs;
        sSc[tid] = sc;
        sSh[tid] = be[tid] - mu * sc;
    }
    __syncthreads();
    for (int i = blockIdx.x * blockDim.x + tid; i < total4; i += gridDim.x * blockDim.x) {
        long base = (long)i * 4;
        int f0 = (int)(base & 127);
        union { uint2 u; _Float16 h[4]; } in;
        in.u = *(const uint2*)&h16[base];
        float y0 = fmaxf(fmaf((float)in.h[0], sSc[f0 + 0], sSh[f0 + 0]), 0.f);
        float y1 = fmaxf(fmaf((float)in.h[1], sSc[f0 + 1], sSh[f0 + 1]), 0.f);
        float y2 = fmaxf(fmaf((float)in.h[2], sSc[f0 + 2], sSh[f0 + 2]), 0.f);
        float y3 = fmaxf(fmaf((float)in.h[3], sSc[f0 + 3], sSh[f0 + 3]), 0.f);
        uint2 o;
        o.x = (u32)(unsigned short)f2h(y0) | ((u32)(unsigned short)f2h(y1) << 16);
        o.y = (u32)(unsigned short)f2h(y2) | ((u32)(unsigned short)f2h(y3) << 16);
        *(uint2*)&hout[base] = o;
    }
}

// ---------------------------------------------------------------------------
// gemm_mid v4: LDS tiles filled by global_load_lds DMA (16B), chunk-swizzled
// layout (slot = (chunk + row) & 15) for conflict-free unpadded ds_read_b128.
// Block 256 = 4 waves; tile 64 nodes x 128 feats; wave = 32 x 64.
// Epilogue: fp16 h_lin store + quad-shuffle-reduced global stat atomics.
// ---------------------------------------------------------------------------
__global__ __launch_bounds__(256, 3) void gemm_mid_kernel(
        const short* __restrict__ hin, const int* __restrict__ idx,
        const short* __restrict__ Wt, const float* __restrict__ bvec,
        unsigned short* __restrict__ h16, float* __restrict__ stats, int N) {
    __shared__ short sA[64 * 128];    // [node][slot*8], swizzled
    __shared__ short sB[128 * 128];   // [feat][slot*8], swizzled

    const int tid = threadIdx.x;
    const int wave = tid >> 6;
    const int lane = tid & 63;
    const int quad = lane >> 4;
    const int l16 = lane & 15;
    const int wm = wave & 1;
    const int wf = wave >> 1;
    const int m0 = blockIdx.x * 64;
    const int sub = lane >> 4;       // staging row-within-group
    const int slotp = lane & 15;     // staging LDS slot position

    f32x4 acc[2][4];
#pragma unroll
    for (int ni = 0; ni < 4; ++ni) {
        float bv = bvec[wf * 64 + ni * 16 + l16];
        acc[0][ni][0] = bv; acc[0][ni][1] = bv; acc[0][ni][2] = bv; acc[0][ni][3] = bv;
        acc[1][ni][0] = bv; acc[1][ni][1] = bv; acc[1][ni][2] = bv; acc[1][ni][3] = bv;
    }

    // per-thread staging metadata: A rows handled by this thread (t=0..3)
    int nodeT[4], rowT[4];
#pragma unroll
    for (int t = 0; t < 4; ++t) {
        nodeT[t] = (wave * 4 + t) * 4 + sub;
        int n = m0 + nodeT[t];
        n = (n < N) ? n : (N - 1);
        nodeT[t + 0] = nodeT[t];     // keep local node id
        rowT[t] = idx[n * 7 + 0];    // prefetch j=0 gather rows
    }

#pragma unroll 1
    for (int j = 0; j < 7; ++j) {
        __syncthreads();   // previous-phase LDS reads done
        // stage B: 8 DMA per thread
#pragma unroll
        for (int t = 0; t < 8; ++t) {
            int f = (wave * 8 + t) * 4 + sub;
            int c = (slotp - f) & 15;
            gl_lds16(Wt + (long)f * 896 + j * 128 + c * 8, &sB[(wave * 8 + t) * 512]);
        }
        // stage A: 4 DMA per thread (gathered rows)
#pragma unroll
        for (int t = 0; t < 4; ++t) {
            int c = (slotp - nodeT[t]) & 15;
            gl_lds16(hin + (long)rowT[t] * 128 + c * 8, &sA[(wave * 4 + t) * 512]);
        }
        // prefetch next j's gather rows while DMA is in flight
        if (j < 6) {
#pragma unroll
            for (int t = 0; t < 4; ++t) {
                int n = m0 + nodeT[t];
                n = (n < N) ? n : (N - 1);
                rowT[t] = idx[n * 7 + j + 1];
            }
        }
        __builtin_amdgcn_s_waitcnt(0);
        __syncthreads();

#pragma unroll
        for (int k0 = 0; k0 < 128; k0 += 32) {
            int cg = (k0 >> 3) + quad;
            f16x8 a[2], b[4];
#pragma unroll
            for (int mi = 0; mi < 2; ++mi) {
                int row = wm * 32 + mi * 16 + l16;
                a[mi] = *(const f16x8*)&sA[row * 128 + ((cg + row) & 15) * 8];
            }
#pragma unroll
            for (int ni = 0; ni < 4; ++ni) {
                int f = wf * 64 + ni * 16 + l16;
                b[ni] = *(const f16x8*)&sB[f * 128 + ((cg + f) & 15) * 8];
            }
#pragma unroll
            for (int ni = 0; ni < 4; ++ni) {
                acc[0][ni] = __builtin_amdgcn_mfma_f32_16x16x32_f16(a[0], b[ni], acc[0][ni], 0, 0, 0);
                acc[1][ni] = __builtin_amdgcn_mfma_f32_16x16x32_f16(a[1], b[ni], acc[1][ni], 0, 0, 0);
            }
        }
    }

    // epilogue: fp16 store + stats (quad-reduced, direct global atomics)
#pragma unroll
    for (int mi = 0; mi < 2; ++mi) {
#pragma unroll
        for (int ni = 0; ni < 4; ++ni) {
            int feat = wf * 64 + ni * 16 + l16;
            float s = 0.f, ss = 0.f;
#pragma unroll
            for (int r = 0; r < 4; ++r) {
                int node = m0 + wm * 32 + mi * 16 + quad * 4 + r;
                float v = acc[mi][ni][r];
                if (node < N) {
                    h16[(long)node * 128 + feat] = (unsigned short)f2h(v);
                    s += v;
                    ss += v * v;
                }
            }
            s += __shfl_xor(s, 16);
            s += __shfl_xor(s, 32);
            ss += __shfl_xor(ss, 16);
            ss += __shfl_xor(ss, 32);
            if (quad == 0) {
                atomicAdd(&stats[feat], s);
                atomicAdd(&stats[128 + feat], ss);
            }
        }
    }
}

// ---------------------------------------------------------------------------
// gemm_final v4: same DMA+swizzle structure; 48-feat B (36 valid), fp32 out.
// Wave = 16 nodes x 48 feats.
// ---------------------------------------------------------------------------
__global__ __launch_bounds__(256, 3) void gemm_final_kernel(
        const short* __restrict__ hin, const int* __restrict__ idx,
        const short* __restrict__ WtF, const float* __restrict__ bl,
        float* __restrict__ out, int N) {
    __shared__ short sA[64 * 128];
    __shared__ short sB[48 * 128];

    const int tid = threadIdx.x;
    const int wave = tid >> 6;
    const int lane = tid & 63;
    const int quad = lane >> 4;
    const int l16 = lane & 15;
    const int m0 = blockIdx.x * 64;
    const int sub = lane >> 4;
    const int slotp = lane & 15;

    f32x4 acc[3];
#pragma unroll
    for (int ni = 0; ni < 3; ++ni) {
        int feat = ni * 16 + l16;
        float bv = (feat < 36) ? bl[feat] : 0.f;
        acc[ni][0] = bv; acc[ni][1] = bv; acc[ni][2] = bv; acc[ni][3] = bv;
    }

    int nodeT[4], rowT[4];
#pragma unroll
    for (int t = 0; t < 4; ++t) {
        nodeT[t] = (wave * 4 + t) * 4 + sub;
        int n = m0 + nodeT[t];
        n = (n < N) ? n : (N - 1);
        rowT[t] = idx[n * 7 + 0];
    }

#pragma unroll 1
    for (int j = 0; j < 7; ++j) {
        __syncthreads();
        // stage B: 48 rows -> 12 wave-loads -> 3 per wave
#pragma unroll
        for (int t = 0; t < 3; ++t) {
            int f = (wave * 3 + t) * 4 + sub;
            int c = (slotp - f) & 15;
            gl_lds16(WtF + (long)f * 896 + j * 128 + c * 8, &sB[(wave * 3 + t) * 512]);
        }
#pragma unroll
        for (int t = 0; t < 4; ++t) {
            int c = (slotp - nodeT[t]) & 15;
            gl_lds16(hin + (long)rowT[t] * 128 + c * 8, &sA[(wave * 4 + t) * 512]);
        }
        if (j < 6) {
#pragma unroll
            for (int t = 0; t < 4; ++t) {
                int n = m0 + nodeT[t];
                n = (n < N) ? n : (N - 1);
                rowT[t] = idx[n * 7 + j + 1];
            }
        }
        __builtin_amdgcn_s_waitcnt(0);
        __syncthreads();

#pragma unroll
        for (int k0 = 0; k0 < 128; k0 += 32) {
            int cg = (k0 >> 3) + quad;
            int row = wave * 16 + l16;
            f16x8 a = *(const f16x8*)&sA[row * 128 + ((cg + row) & 15) * 8];
            f16x8 b[3];
#pragma unroll
            for (int ni = 0; ni < 3; ++ni) {
                int f = ni * 16 + l16;
                b[ni] = *(const f16x8*)&sB[f * 128 + ((cg + f) & 15) * 8];
            }
#pragma unroll
            for (int ni = 0; ni < 3; ++ni)
                acc[ni] = __builtin_amdgcn_mfma_f32_16x16x32_f16(a, b[ni], acc[ni], 0, 0, 0);
        }
    }

#pragma unroll
    for (int ni = 0; ni < 3; ++ni) {
        int feat = ni * 16 + l16;
        if (feat < 36) {
#pragma unroll
            for (int r = 0; r < 4; ++r) {
                int node = m0 + wave * 16 + quad * 4 + r;
                if (node < N) out[(long)node * 36 + feat] = acc[ni][r];
            }
        }
    }
}

// ---------------------------------------------------------------------------
extern "C" void kernel_launch(void* const* d_in, const int* in_sizes, int n_in,
                              void* d_out, int out_size, void* d_ws, size_t ws_size,
                              hipStream_t stream) {
    const float* x   = (const float*)d_in[0];
    const int*   idx = (const int*)d_in[1];
    const float* W0  = (const float*)d_in[2];
    const float* b0  = (const float*)d_in[3];
    const float* g0  = (const float*)d_in[4];
    const float* be0 = (const float*)d_in[5];
    const float* Wm  = (const float*)d_in[6];
    const float* bm  = (const float*)d_in[7];
    const float* gm  = (const float*)d_in[8];
    const float* bem = (const float*)d_in[9];
    const float* Wl  = (const float*)d_in[10];
    const float* bl  = (const float*)d_in[11];
    float* out = (float*)d_out;

    const int N = in_sizes[0] / 3;          // 40962
    const float invN = 1.0f / (float)N;

    char* ws = (char*)d_ws;
    size_t off = 0;
    auto alloc = [&](size_t bytes) -> void* {
        void* p = ws + off;
        off = (off + bytes + 255) & ~(size_t)255;
        return p;
    };
    short* WtM   = (short*)alloc(14UL * 128 * 896 * 2);
    short* WtF   = (short*)alloc(48UL * 896 * 2);
    float* stats = (float*)alloc(15UL * 256 * 4);
    unsigned short* hlin16 = (unsigned short*)alloc((size_t)N * 128 * 2); // pre-BN
    unsigned short* hA     = (unsigned short*)alloc((size_t)N * 128 * 2); // post-BN
    unsigned short* hB     = (unsigned short*)alloc((size_t)N * 128 * 2);

    {
        long total = 14L * 896 * 128 + 48L * 896 + 15L * 256;
        int blocks = (int)((total + 255) / 256);
        prep_kernel<<<blocks, 256, 0, stream>>>(Wm, Wl, WtM, WtF, stats);
    }

    layer0_kernel<<<1024, 256, 0, stream>>>(x, idx, W0, b0, hlin16, stats, N);

    int total4 = N * 32;  // N*128/4
    bn_relu_kernel<<<1024, 256, 0, stream>>>(hlin16, stats, g0, be0, hA, total4, invN);

    const int gblocks = (N + 63) / 64;
    unsigned short* hin = hA;
    unsigned short* hout = hB;
    for (int L = 0; L < 14; ++L) {
        gemm_mid_kernel<<<gblocks, 256, 0, stream>>>(
            (const short*)hin, idx, WtM + (size_t)L * 128 * 896, bm + L * 128,
            hlin16, stats + (L + 1) * 256, N);
        bn_relu_kernel<<<1024, 256, 0, stream>>>(
            hlin16, stats + (L + 1) * 256, gm + L * 128, bem + L * 128,
            hout, total4, invN);
        unsigned short* t = hin; hin = hout; hout = t;
    }

    gemm_final_kernel<<<gblocks, 256, 0, stream>>>((const short*)hin, idx, WtF, bl, out, N);
}

// Round 5
// 1167.131 us; speedup vs baseline: 1.1280x; 1.1280x over previous
//
#include <hip/hip_runtime.h>

typedef _Float16 f16x8 __attribute__((ext_vector_type(8)));
typedef float f32x4 __attribute__((ext_vector_type(4)));
typedef unsigned int u32;

#define EPS 1e-5f

__device__ __forceinline__ short f2h(float x) {
    _Float16 h = (_Float16)x;   // RNE v_cvt_f16_f32
    union { _Float16 h; short s; } u;
    u.h = h;
    return u.s;
}

// ---------------------------------------------------------------------------
// prep: output-linear transpose+convert. WtM[l][f][k] fp16 <- Wm[l][k][f],
// WtF[f][k] fp16 (f padded to 48), stats zeroed.
// ---------------------------------------------------------------------------
__global__ __launch_bounds__(256) void prep_kernel(
        const float* __restrict__ Wm, const float* __restrict__ Wl,
        short* __restrict__ WtM, short* __restrict__ WtF,
        float* __restrict__ stats) {
    const long T1 = 14L * 896 * 128;
    const long T2 = 48L * 896;
    const long T3 = 15L * 256;
    long i = (long)blockIdx.x * blockDim.x + threadIdx.x;
    if (i < T1) {
        long l = i / 114688;
        long r = i % 114688;
        long f = r / 896;
        long k = r % 896;
        WtM[i] = f2h(Wm[l * 114688 + k * 128 + f]);
    } else if (i < T1 + T2) {
        long j = i - T1;
        long f = j / 896;
        long k = j % 896;
        WtF[j] = (f < 36) ? f2h(Wl[k * 36 + f]) : (short)0;
    } else if (i < T1 + T2 + T3) {
        stats[i - T1 - T2] = 0.0f;
    }
}

// ---------------------------------------------------------------------------
// layer0: wave-per-node, barrier-free after W0 staging. Writes fp16 pre-BN
// h_lin + fp32 stats.
// ---------------------------------------------------------------------------
__global__ __launch_bounds__(256) void layer0_kernel(
        const float* __restrict__ x, const int* __restrict__ idx,
        const float* __restrict__ W0, const float* __restrict__ b0,
        unsigned short* __restrict__ h16, float* __restrict__ stats, int N) {
    __shared__ float sW[21 * 128];
    __shared__ float sstat[256];
    const int tid = threadIdx.x;
    const int lane = tid & 63;
    const int wave = tid >> 6;
    for (int i = tid; i < 21 * 128; i += 256) sW[i] = W0[i];
    sstat[tid] = 0.f;
    __syncthreads();

    const int f0 = lane, f1 = lane + 64;
    const float bb0 = b0[f0], bb1 = b0[f1];
    float s0 = 0.f, ss0 = 0.f, s1 = 0.f, ss1 = 0.f;

    const int gw = blockIdx.x * 4 + wave;
    const int nw = gridDim.x * 4;
    for (int n = gw; n < N; n += nw) {
        float a0 = bb0, a1 = bb1;
#pragma unroll
        for (int j = 0; j < 7; ++j) {
            int r = idx[n * 7 + j];
            float x0 = x[(long)r * 3 + 0];
            float x1 = x[(long)r * 3 + 1];
            float x2 = x[(long)r * 3 + 2];
            int k = j * 3;
            a0 = fmaf(x0, sW[(k + 0) * 128 + f0], a0);
            a0 = fmaf(x1, sW[(k + 1) * 128 + f0], a0);
            a0 = fmaf(x2, sW[(k + 2) * 128 + f0], a0);
            a1 = fmaf(x0, sW[(k + 0) * 128 + f1], a1);
            a1 = fmaf(x1, sW[(k + 1) * 128 + f1], a1);
            a1 = fmaf(x2, sW[(k + 2) * 128 + f1], a1);
        }
        h16[(long)n * 128 + f0] = (unsigned short)f2h(a0);
        h16[(long)n * 128 + f1] = (unsigned short)f2h(a1);
        s0 += a0; ss0 += a0 * a0;
        s1 += a1; ss1 += a1 * a1;
    }
    atomicAdd(&sstat[f0], s0);
    atomicAdd(&sstat[128 + f0], ss0);
    atomicAdd(&sstat[f1], s1);
    atomicAdd(&sstat[128 + f1], ss1);
    __syncthreads();
    if (tid < 256) atomicAdd(&stats[tid], sstat[tid]);
}

// ---------------------------------------------------------------------------
// bn_relu: fp16 in (pre-BN), fp16 out = relu(sc*h + sh).
// ---------------------------------------------------------------------------
__global__ __launch_bounds__(256) void bn_relu_kernel(
        const unsigned short* __restrict__ h16, const float* __restrict__ stats,
        const float* __restrict__ g, const float* __restrict__ be,
        unsigned short* __restrict__ hout, int total4, float invN) {
    __shared__ float sSc[128], sSh[128];
    const int tid = threadIdx.x;
    if (tid < 128) {
        float mu = stats[tid] * invN;
        float var = stats[128 + tid] * invN - mu * mu;
        float rs = rsqrtf(var + EPS);
        float sc = g[tid] * rs;
        sSc[tid] = sc;
        sSh[tid] = be[tid] - mu * sc;
    }
    __syncthreads();
    for (int i = blockIdx.x * blockDim.x + tid; i < total4; i += gridDim.x * blockDim.x) {
        long base = (long)i * 4;
        int f0 = (int)(base & 127);
        union { uint2 u; _Float16 h[4]; } in;
        in.u = *(const uint2*)&h16[base];
        float y0 = fmaxf(fmaf((float)in.h[0], sSc[f0 + 0], sSh[f0 + 0]), 0.f);
        float y1 = fmaxf(fmaf((float)in.h[1], sSc[f0 + 1], sSh[f0 + 1]), 0.f);
        float y2 = fmaxf(fmaf((float)in.h[2], sSc[f0 + 2], sSh[f0 + 2]), 0.f);
        float y3 = fmaxf(fmaf((float)in.h[3], sSc[f0 + 3], sSh[f0 + 3]), 0.f);
        uint2 o;
        o.x = (u32)(unsigned short)f2h(y0) | ((u32)(unsigned short)f2h(y1) << 16);
        o.y = (u32)(unsigned short)f2h(y2) | ((u32)(unsigned short)f2h(y3) << 16);
        *(uint2*)&hout[base] = o;
    }
}

// ---------------------------------------------------------------------------
// gemm_mid v5: j-flattened. A-tile = 32 nodes x 896 (all 7 gathered rows) in
// padded LDS (stride 904 halves -> +4 banks/row, conflict-free class), staged
// ONCE per block (2 barriers total). K-loop = 28 barrier-free MFMA steps; B
// read straight from L2-hot Wt with 1-step register prefetch (16 full 64B
// lines per instr). Block 256 = 4 waves; wave = 32 nodes x 32 feats.
// ---------------------------------------------------------------------------
__global__ __launch_bounds__(256, 2) void gemm_mid_kernel(
        const short* __restrict__ hin, const int* __restrict__ idx,
        const short* __restrict__ Wt, const float* __restrict__ bvec,
        unsigned short* __restrict__ h16, float* __restrict__ stats, int N) {
    __shared__ short sA[32 * 904];   // 57,856 B

    const int tid = threadIdx.x;
    const int wave = tid >> 6;
    const int lane = tid & 63;
    const int quad = lane >> 4;
    const int l16 = lane & 15;
    const int m0 = blockIdx.x * 32;

    // ---- stage A: 32 nodes x 7 rows x 16 chunks = 3584 chunks, 14/thread ----
    int rows[14];
#pragma unroll
    for (int t = 0; t < 14; ++t) {
        int i = tid + t * 256;
        int n = i / 112;             // node 0..31
        int rem = i - n * 112;
        int j = rem >> 4;            // neighbor 0..6
        int gn = m0 + n;
        gn = (gn < N) ? gn : (N - 1);
        rows[t] = idx[gn * 7 + j];
    }
    f16x8 v[14];
#pragma unroll
    for (int t = 0; t < 14; ++t) {
        int i = tid + t * 256;
        int rem = i % 112;
        int c = rem & 15;
        v[t] = *(const f16x8*)(hin + (long)rows[t] * 128 + c * 8);
    }
#pragma unroll
    for (int t = 0; t < 14; ++t) {
        int i = tid + t * 256;
        int n = i / 112;
        int rem = i - n * 112;       // j*16 + c
        *(f16x8*)&sA[n * 904 + rem * 8] = v[t];
    }

    // acc init with bias
    const int fb = wave * 32 + l16;          // ni=0 feat row; ni=1 is fb+16
    f32x4 acc[2][2];
#pragma unroll
    for (int ni = 0; ni < 2; ++ni) {
        float bv = bvec[fb + ni * 16];
        acc[0][ni][0] = bv; acc[0][ni][1] = bv; acc[0][ni][2] = bv; acc[0][ni][3] = bv;
        acc[1][ni][0] = bv; acc[1][ni][1] = bv; acc[1][ni][2] = bv; acc[1][ni][3] = bv;
    }

    __syncthreads();

    // ---- K-loop: 28 steps, no barriers; B prefetched 1 step ahead ----
    const short* bp0 = Wt + (long)fb * 896 + quad * 8;
    const short* bp1 = bp0 + 16 * 896;
    f16x8 b0 = *(const f16x8*)bp0;
    f16x8 b1 = *(const f16x8*)bp1;
#pragma unroll
    for (int ks = 0; ks < 28; ++ks) {
        f16x8 a0 = *(const f16x8*)&sA[l16 * 904 + ks * 32 + quad * 8];
        f16x8 a1 = *(const f16x8*)&sA[(16 + l16) * 904 + ks * 32 + quad * 8];
        f16x8 nb0, nb1;
        if (ks < 27) {
            nb0 = *(const f16x8*)(bp0 + (ks + 1) * 32);
            nb1 = *(const f16x8*)(bp1 + (ks + 1) * 32);
        }
        acc[0][0] = __builtin_amdgcn_mfma_f32_16x16x32_f16(a0, b0, acc[0][0], 0, 0, 0);
        acc[1][0] = __builtin_amdgcn_mfma_f32_16x16x32_f16(a1, b0, acc[1][0], 0, 0, 0);
        acc[0][1] = __builtin_amdgcn_mfma_f32_16x16x32_f16(a0, b1, acc[0][1], 0, 0, 0);
        acc[1][1] = __builtin_amdgcn_mfma_f32_16x16x32_f16(a1, b1, acc[1][1], 0, 0, 0);
        b0 = nb0; b1 = nb1;
    }

    // ---- epilogue: fp16 store + quad-reduced global stat atomics ----
#pragma unroll
    for (int ni = 0; ni < 2; ++ni) {
        int feat = fb + ni * 16;
        float s = 0.f, ss = 0.f;
#pragma unroll
        for (int mi = 0; mi < 2; ++mi) {
#pragma unroll
            for (int r = 0; r < 4; ++r) {
                int node = m0 + mi * 16 + quad * 4 + r;
                float vv = acc[mi][ni][r];
                if (node < N) {
                    h16[(long)node * 128 + feat] = (unsigned short)f2h(vv);
                    s += vv;
                    ss += vv * vv;
                }
            }
        }
        s += __shfl_xor(s, 16);
        s += __shfl_xor(s, 32);
        ss += __shfl_xor(ss, 16);
        ss += __shfl_xor(ss, 32);
        if (quad == 0) {
            atomicAdd(&stats[feat], s);
            atomicAdd(&stats[128 + feat], ss);
        }
    }
}

// ---------------------------------------------------------------------------
// gemm_final v5: same j-flattened structure. Block 128 = 2 waves; wave =
// 16 nodes x 48 feats (3 ni tiles); M-tile 32 nodes.
// ---------------------------------------------------------------------------
__global__ __launch_bounds__(128, 2) void gemm_final_kernel(
        const short* __restrict__ hin, const int* __restrict__ idx,
        const short* __restrict__ WtF, const float* __restrict__ bl,
        float* __restrict__ out, int N) {
    __shared__ short sA[32 * 904];

    const int tid = threadIdx.x;
    const int wave = tid >> 6;
    const int lane = tid & 63;
    const int quad = lane >> 4;
    const int l16 = lane & 15;
    const int m0 = blockIdx.x * 32;

    // stage A: 3584 chunks over 128 threads = 28/thread, two passes of 14
#pragma unroll
    for (int p = 0; p < 2; ++p) {
        int rows[14];
#pragma unroll
        for (int t = 0; t < 14; ++t) {
            int i = tid + (p * 14 + t) * 128;
            int n = i / 112;
            int rem = i - n * 112;
            int j = rem >> 4;
            int gn = m0 + n;
            gn = (gn < N) ? gn : (N - 1);
            rows[t] = idx[gn * 7 + j];
        }
        f16x8 v[14];
#pragma unroll
        for (int t = 0; t < 14; ++t) {
            int i = tid + (p * 14 + t) * 128;
            int rem = i % 112;
            int c = rem & 15;
            v[t] = *(const f16x8*)(hin + (long)rows[t] * 128 + c * 8);
        }
#pragma unroll
        for (int t = 0; t < 14; ++t) {
            int i = tid + (p * 14 + t) * 128;
            int n = i / 112;
            int rem = i - n * 112;
            *(f16x8*)&sA[n * 904 + rem * 8] = v[t];
        }
    }

    f32x4 acc[3];
#pragma unroll
    for (int ni = 0; ni < 3; ++ni) {
        int feat = ni * 16 + l16;
        float bv = (feat < 36) ? bl[feat] : 0.f;
        acc[ni][0] = bv; acc[ni][1] = bv; acc[ni][2] = bv; acc[ni][3] = bv;
    }

    __syncthreads();

    const short* bp = WtF + (long)l16 * 896 + quad * 8;
#pragma unroll
    for (int ks = 0; ks < 28; ++ks) {
        f16x8 a = *(const f16x8*)&sA[(wave * 16 + l16) * 904 + ks * 32 + quad * 8];
        f16x8 b[3];
#pragma unroll
        for (int ni = 0; ni < 3; ++ni)
            b[ni] = *(const f16x8*)(bp + (long)ni * 16 * 896 + ks * 32);
#pragma unroll
        for (int ni = 0; ni < 3; ++ni)
            acc[ni] = __builtin_amdgcn_mfma_f32_16x16x32_f16(a, b[ni], acc[ni], 0, 0, 0);
    }

#pragma unroll
    for (int ni = 0; ni < 3; ++ni) {
        int feat = ni * 16 + l16;
        if (feat < 36) {
#pragma unroll
            for (int r = 0; r < 4; ++r) {
                int node = m0 + wave * 16 + quad * 4 + r;
                if (node < N) out[(long)node * 36 + feat] = acc[ni][r];
            }
        }
    }
}

// ---------------------------------------------------------------------------
extern "C" void kernel_launch(void* const* d_in, const int* in_sizes, int n_in,
                              void* d_out, int out_size, void* d_ws, size_t ws_size,
                              hipStream_t stream) {
    const float* x   = (const float*)d_in[0];
    const int*   idx = (const int*)d_in[1];
    const float* W0  = (const float*)d_in[2];
    const float* b0  = (const float*)d_in[3];
    const float* g0  = (const float*)d_in[4];
    const float* be0 = (const float*)d_in[5];
    const float* Wm  = (const float*)d_in[6];
    const float* bm  = (const float*)d_in[7];
    const float* gm  = (const float*)d_in[8];
    const float* bem = (const float*)d_in[9];
    const float* Wl  = (const float*)d_in[10];
    const float* bl  = (const float*)d_in[11];
    float* out = (float*)d_out;

    const int N = in_sizes[0] / 3;          // 40962
    const float invN = 1.0f / (float)N;

    char* ws = (char*)d_ws;
    size_t off = 0;
    auto alloc = [&](size_t bytes) -> void* {
        void* p = ws + off;
        off = (off + bytes + 255) & ~(size_t)255;
        return p;
    };
    short* WtM   = (short*)alloc(14UL * 128 * 896 * 2);
    short* WtF   = (short*)alloc(48UL * 896 * 2);
    float* stats = (float*)alloc(15UL * 256 * 4);
    unsigned short* hlin16 = (unsigned short*)alloc((size_t)N * 128 * 2); // pre-BN
    unsigned short* hA     = (unsigned short*)alloc((size_t)N * 128 * 2); // post-BN
    unsigned short* hB     = (unsigned short*)alloc((size_t)N * 128 * 2);

    {
        long total = 14L * 896 * 128 + 48L * 896 + 15L * 256;
        int blocks = (int)((total + 255) / 256);
        prep_kernel<<<blocks, 256, 0, stream>>>(Wm, Wl, WtM, WtF, stats);
    }

    layer0_kernel<<<1024, 256, 0, stream>>>(x, idx, W0, b0, hlin16, stats, N);

    int total4 = N * 32;  // N*128/4
    bn_relu_kernel<<<1024, 256, 0, stream>>>(hlin16, stats, g0, be0, hA, total4, invN);

    const int gblocks = (N + 31) / 32;      // 1281
    unsigned short* hin = hA;
    unsigned short* hout = hB;
    for (int L = 0; L < 14; ++L) {
        gemm_mid_kernel<<<gblocks, 256, 0, stream>>>(
            (const short*)hin, idx, WtM + (size_t)L * 128 * 896, bm + L * 128,
            hlin16, stats + (L + 1) * 256, N);
        bn_relu_kernel<<<1024, 256, 0, stream>>>(
            hlin16, stats + (L + 1) * 256, gm + L * 128, bem + L * 128,
            hout, total4, invN);
        unsigned short* t = hin; hin = hout; hout = t;
    }

    gemm_final_kernel<<<gblocks, 128, 0, stream>>>((const short*)hin, idx, WtF, bl, out, N);
}

// Round 6
// 1027.034 us; speedup vs baseline: 1.2819x; 1.1364x over previous
//
#include <hip/hip_runtime.h>

typedef _Float16 f16x8 __attribute__((ext_vector_type(8)));
typedef float f32x4 __attribute__((ext_vector_type(4)));
typedef unsigned int u32;

#define EPS 1e-5f

__device__ __forceinline__ short f2h(float x) {
    _Float16 h = (_Float16)x;   // RNE v_cvt_f16_f32
    union { _Float16 h; short s; } u;
    u.h = h;
    return u.s;
}

// async global->LDS DMA, 16 B per lane. LDS dest = wave-uniform base + lane*16.
__device__ __forceinline__ void gl_lds16(const void* g, void* l) {
    __builtin_amdgcn_global_load_lds(
        (const __attribute__((address_space(1))) u32*)g,
        (__attribute__((address_space(3))) u32*)l, 16, 0, 0);
}

// ---------------------------------------------------------------------------
// prep: WtM[l][f][k] fp16 <- Wm[l][k][f]; WtF[f][k] fp16 (f padded to 48);
// stats zeroed.
// ---------------------------------------------------------------------------
__global__ __launch_bounds__(256) void prep_kernel(
        const float* __restrict__ Wm, const float* __restrict__ Wl,
        short* __restrict__ WtM, short* __restrict__ WtF,
        float* __restrict__ stats) {
    const long T1 = 14L * 896 * 128;
    const long T2 = 48L * 896;
    const long T3 = 15L * 256;
    long i = (long)blockIdx.x * blockDim.x + threadIdx.x;
    if (i < T1) {
        long l = i / 114688;
        long r = i % 114688;
        long f = r / 896;
        long k = r % 896;
        WtM[i] = f2h(Wm[l * 114688 + k * 128 + f]);
    } else if (i < T1 + T2) {
        long j = i - T1;
        long f = j / 896;
        long k = j % 896;
        WtF[j] = (f < 36) ? f2h(Wl[k * 36 + f]) : (short)0;
    } else if (i < T1 + T2 + T3) {
        stats[i - T1 - T2] = 0.0f;
    }
}

// ---------------------------------------------------------------------------
// layer0: wave-per-node, barrier-free after W0 staging. fp16 pre-BN h + stats.
// ---------------------------------------------------------------------------
__global__ __launch_bounds__(256) void layer0_kernel(
        const float* __restrict__ x, const int* __restrict__ idx,
        const float* __restrict__ W0, const float* __restrict__ b0,
        unsigned short* __restrict__ h16, float* __restrict__ stats, int N) {
    __shared__ float sW[21 * 128];
    __shared__ float sstat[256];
    const int tid = threadIdx.x;
    const int lane = tid & 63;
    const int wave = tid >> 6;
    for (int i = tid; i < 21 * 128; i += 256) sW[i] = W0[i];
    sstat[tid] = 0.f;
    __syncthreads();

    const int f0 = lane, f1 = lane + 64;
    const float bb0 = b0[f0], bb1 = b0[f1];
    float s0 = 0.f, ss0 = 0.f, s1 = 0.f, ss1 = 0.f;

    const int gw = blockIdx.x * 4 + wave;
    const int nw = gridDim.x * 4;
    for (int n = gw; n < N; n += nw) {
        float a0 = bb0, a1 = bb1;
#pragma unroll
        for (int j = 0; j < 7; ++j) {
            int r = idx[n * 7 + j];
            float x0 = x[(long)r * 3 + 0];
            float x1 = x[(long)r * 3 + 1];
            float x2 = x[(long)r * 3 + 2];
            int k = j * 3;
            a0 = fmaf(x0, sW[(k + 0) * 128 + f0], a0);
            a0 = fmaf(x1, sW[(k + 1) * 128 + f0], a0);
            a0 = fmaf(x2, sW[(k + 2) * 128 + f0], a0);
            a1 = fmaf(x0, sW[(k + 0) * 128 + f1], a1);
            a1 = fmaf(x1, sW[(k + 1) * 128 + f1], a1);
            a1 = fmaf(x2, sW[(k + 2) * 128 + f1], a1);
        }
        h16[(long)n * 128 + f0] = (unsigned short)f2h(a0);
        h16[(long)n * 128 + f1] = (unsigned short)f2h(a1);
        s0 += a0; ss0 += a0 * a0;
        s1 += a1; ss1 += a1 * a1;
    }
    atomicAdd(&sstat[f0], s0);
    atomicAdd(&sstat[128 + f0], ss0);
    atomicAdd(&sstat[f1], s1);
    atomicAdd(&sstat[128 + f1], ss1);
    __syncthreads();
    if (tid < 256) atomicAdd(&stats[tid], sstat[tid]);
}

// ---------------------------------------------------------------------------
// bn_gather: G[m, j*128+f] = relu(sc[f]*h16[idx[m*7+j]*128+f] + sh[f]).
// One thread per 16-B chunk (8 feats): 4.6M independent threads -> gather
// latency hidden by pure TLP; writes perfectly coalesced (G linear = t*8).
// ---------------------------------------------------------------------------
__global__ __launch_bounds__(256) void bn_gather_kernel(
        const unsigned short* __restrict__ h16, const float* __restrict__ stats,
        const float* __restrict__ g, const float* __restrict__ be,
        const int* __restrict__ idx, unsigned short* __restrict__ G,
        int total, float invN) {
    __shared__ float sSc[128], sSh[128];
    const int tid = threadIdx.x;
    if (tid < 128) {
        float mu = stats[tid] * invN;
        float var = stats[128 + tid] * invN - mu * mu;
        float rs = rsqrtf(var + EPS);
        float sc = g[tid] * rs;
        sSc[tid] = sc;
        sSh[tid] = be[tid] - mu * sc;
    }
    __syncthreads();
    for (int t = blockIdx.x * blockDim.x + tid; t < total; t += gridDim.x * blockDim.x) {
        int m = t / 112;               // node
        int rem = t - m * 112;
        int j = rem >> 4;              // neighbor
        int c = rem & 15;              // 8-feat chunk
        int row = idx[m * 7 + j];
        f16x8 v = *(const f16x8*)&h16[(long)row * 128 + c * 8];
        union { f16x8 h; unsigned short us[8]; } o;
#pragma unroll
        for (int e = 0; e < 8; ++e) {
            int f = c * 8 + e;
            float y = fmaxf(fmaf((float)v[e], sSc[f], sSh[f]), 0.f);
            o.us[e] = (unsigned short)f2h(y);
        }
        *(f16x8*)&G[(long)t * 8] = o.h;
    }
}

// ---------------------------------------------------------------------------
// gemm_g: h_lin[N,128] = G[N,896] @ W[896,128] + b. PURE dense GEMM, no
// indirection. Block 256 = 4 waves (2x2), tile 128 nodes x 128 feats, BK=64.
// A,B staged via global_load_lds 16B DMA with XOR chunk swizzle
// (slot = chunk ^ (row&7)) -> conflict-free ds_read_b128 fragments.
// Epilogue: fp16 store + per-feature stats (quad-shuffle + global atomic).
// ---------------------------------------------------------------------------
__global__ __launch_bounds__(256, 2) void gemm_g_kernel(
        const unsigned short* __restrict__ G, const short* __restrict__ Wt,
        const float* __restrict__ bvec, unsigned short* __restrict__ h16,
        float* __restrict__ stats, int N) {
    __shared__ short sA[128 * 64];   // 16 KB: [row][slot*8]
    __shared__ short sB[128 * 64];   // 16 KB

    const int tid = threadIdx.x;
    const int wave = tid >> 6;
    const int lane = tid & 63;
    const int quad = lane >> 4;
    const int l16 = lane & 15;
    const int wm = wave & 1;         // node half (64)
    const int wf = wave >> 1;        // feat half (64)
    const int m0 = blockIdx.x * 128;

    // staging: each wave fills 32 rows of sA and 32 rows of sB per slab,
    // in 4 DMAs of 8 rows. lane -> (row srow, stored slot lane&7).
    const int srow = lane >> 3;
    const int schunk = (lane & 7) ^ srow;   // global chunk to fetch

    long arow[4], brow[4];
#pragma unroll
    for (int d = 0; d < 4; ++d) {
        int r = m0 + wave * 32 + d * 8 + srow;
        r = (r < N) ? r : (N - 1);
        arow[d] = (long)r * 896;
        brow[d] = (long)(wave * 32 + d * 8 + srow) * 896;
    }

    f32x4 acc[4][4];
#pragma unroll
    for (int ni = 0; ni < 4; ++ni) {
        float bv = bvec[wf * 64 + ni * 16 + l16];
#pragma unroll
        for (int mi = 0; mi < 4; ++mi) {
            acc[mi][ni][0] = bv; acc[mi][ni][1] = bv;
            acc[mi][ni][2] = bv; acc[mi][ni][3] = bv;
        }
    }

#pragma unroll 1
    for (int ks = 0; ks < 14; ++ks) {
        __syncthreads();                      // prev slab reads done
        const int kb = ks * 64 + schunk * 8;  // halves offset in row
#pragma unroll
        for (int d = 0; d < 4; ++d)
            gl_lds16(G + arow[d] + kb, &sA[(wave * 32 + d * 8) * 64]);
#pragma unroll
        for (int d = 0; d < 4; ++d)
            gl_lds16(Wt + brow[d] + kb, &sB[(wave * 32 + d * 8) * 64]);
        __builtin_amdgcn_s_waitcnt(0);
        __syncthreads();

#pragma unroll
        for (int s = 0; s < 2; ++s) {
            f16x8 a[4], b[4];
#pragma unroll
            for (int mi = 0; mi < 4; ++mi) {
                int r = wm * 64 + mi * 16 + l16;
                int c = s * 4 + quad;
                a[mi] = *(const f16x8*)&sA[r * 64 + ((c ^ (r & 7)) * 8)];
            }
#pragma unroll
            for (int ni = 0; ni < 4; ++ni) {
                int f = wf * 64 + ni * 16 + l16;
                int c = s * 4 + quad;
                b[ni] = *(const f16x8*)&sB[f * 64 + ((c ^ (f & 7)) * 8)];
            }
#pragma unroll
            for (int mi = 0; mi < 4; ++mi)
#pragma unroll
                for (int ni = 0; ni < 4; ++ni)
                    acc[mi][ni] = __builtin_amdgcn_mfma_f32_16x16x32_f16(
                        a[mi], b[ni], acc[mi][ni], 0, 0, 0);
        }
    }

    // epilogue: fp16 store + stats
#pragma unroll
    for (int ni = 0; ni < 4; ++ni) {
        int feat = wf * 64 + ni * 16 + l16;
        float s = 0.f, ss = 0.f;
#pragma unroll
        for (int mi = 0; mi < 4; ++mi) {
#pragma unroll
            for (int r = 0; r < 4; ++r) {
                int node = m0 + wm * 64 + mi * 16 + quad * 4 + r;
                float v = acc[mi][ni][r];
                if (node < N) {
                    h16[(long)node * 128 + feat] = (unsigned short)f2h(v);
                    s += v;
                    ss += v * v;
                }
            }
        }
        s += __shfl_xor(s, 16);
        s += __shfl_xor(s, 32);
        ss += __shfl_xor(ss, 16);
        ss += __shfl_xor(ss, 32);
        if (quad == 0) {
            atomicAdd(&stats[feat], s);
            atomicAdd(&stats[128 + feat], ss);
        }
    }
}

// ---------------------------------------------------------------------------
// gemm_final: out[N,36] = G[N,896] @ Wl + bl. Streaming (G rows contiguous),
// 28 unrolled k-steps, no LDS. Block 256 = 4 waves x 16 nodes; 64 nodes/block.
// ---------------------------------------------------------------------------
__global__ __launch_bounds__(256, 2) void gemm_final_kernel(
        const unsigned short* __restrict__ G, const short* __restrict__ WtF,
        const float* __restrict__ bl, float* __restrict__ out, int N) {
    const int tid = threadIdx.x;
    const int wave = tid >> 6;
    const int lane = tid & 63;
    const int quad = lane >> 4;
    const int l16 = lane & 15;
    const int m0 = blockIdx.x * 64;

    const int n0 = m0 + wave * 16 + l16;
    const long arow = (long)((n0 < N) ? n0 : (N - 1)) * 896;

    f32x4 acc[3];
#pragma unroll
    for (int ni = 0; ni < 3; ++ni) {
        int feat = ni * 16 + l16;
        float bv = (feat < 36) ? bl[feat] : 0.f;
        acc[ni][0] = bv; acc[ni][1] = bv; acc[ni][2] = bv; acc[ni][3] = bv;
    }

    const short* bp = WtF + (long)l16 * 896 + quad * 8;
#pragma unroll
    for (int ks = 0; ks < 28; ++ks) {
        f16x8 a = *(const f16x8*)&G[arow + ks * 32 + quad * 8];
        f16x8 b[3];
#pragma unroll
        for (int ni = 0; ni < 3; ++ni)
            b[ni] = *(const f16x8*)(bp + (long)ni * 16 * 896 + ks * 32);
#pragma unroll
        for (int ni = 0; ni < 3; ++ni)
            acc[ni] = __builtin_amdgcn_mfma_f32_16x16x32_f16(a, b[ni], acc[ni], 0, 0, 0);
    }

#pragma unroll
    for (int ni = 0; ni < 3; ++ni) {
        int feat = ni * 16 + l16;
        if (feat < 36) {
#pragma unroll
            for (int r = 0; r < 4; ++r) {
                int node = m0 + wave * 16 + quad * 4 + r;
                if (node < N) out[(long)node * 36 + feat] = acc[ni][r];
            }
        }
    }
}

// ---------------------------------------------------------------------------
extern "C" void kernel_launch(void* const* d_in, const int* in_sizes, int n_in,
                              void* d_out, int out_size, void* d_ws, size_t ws_size,
                              hipStream_t stream) {
    const float* x   = (const float*)d_in[0];
    const int*   idx = (const int*)d_in[1];
    const float* W0  = (const float*)d_in[2];
    const float* b0  = (const float*)d_in[3];
    const float* g0  = (const float*)d_in[4];
    const float* be0 = (const float*)d_in[5];
    const float* Wm  = (const float*)d_in[6];
    const float* bm  = (const float*)d_in[7];
    const float* gm  = (const float*)d_in[8];
    const float* bem = (const float*)d_in[9];
    const float* Wl  = (const float*)d_in[10];
    const float* bl  = (const float*)d_in[11];
    float* out = (float*)d_out;

    const int N = in_sizes[0] / 3;          // 40962
    const float invN = 1.0f / (float)N;

    char* ws = (char*)d_ws;
    size_t off = 0;
    auto alloc = [&](size_t bytes) -> void* {
        void* p = ws + off;
        off = (off + bytes + 255) & ~(size_t)255;
        return p;
    };
    short* WtM   = (short*)alloc(14UL * 128 * 896 * 2);
    short* WtF   = (short*)alloc(48UL * 896 * 2);
    float* stats = (float*)alloc(15UL * 256 * 4);
    unsigned short* hlin16 = (unsigned short*)alloc((size_t)N * 128 * 2);  // pre-BN h
    unsigned short* G      = (unsigned short*)alloc((size_t)N * 896 * 2);  // gathered+BN

    {
        long total = 14L * 896 * 128 + 48L * 896 + 15L * 256;
        int blocks = (int)((total + 255) / 256);
        prep_kernel<<<blocks, 256, 0, stream>>>(Wm, Wl, WtM, WtF, stats);
    }

    layer0_kernel<<<1024, 256, 0, stream>>>(x, idx, W0, b0, hlin16, stats, N);

    const int gtotal = N * 112;             // 16-B chunks of G
    const int gemmblocks = (N + 127) / 128; // 321

    bn_gather_kernel<<<2048, 256, 0, stream>>>(hlin16, stats, g0, be0, idx, G, gtotal, invN);

    for (int L = 0; L < 14; ++L) {
        gemm_g_kernel<<<gemmblocks, 256, 0, stream>>>(
            G, WtM + (size_t)L * 128 * 896, bm + L * 128,
            hlin16, stats + (L + 1) * 256, N);
        bn_gather_kernel<<<2048, 256, 0, stream>>>(
            hlin16, stats + (L + 1) * 256, gm + L * 128, bem + L * 128,
            idx, G, gtotal, invN);
    }

    gemm_final_kernel<<<(N + 63) / 64, 256, 0, stream>>>(G, WtF, bl, out, N);
}